// Round 12
// baseline (1776.175 us; speedup 1.0000x reference)
//
#include <hip/hip_runtime.h>
#include <hip/hip_bf16.h>
#include <math.h>

// ---------------------------------------------------------------------------
// D=256, LVL=17, MIX=20. N nodes = 2^18-1; internal = 2^17-1 = 131071.
//  * Encoder reads ORIGINAL Feature -> only root's encoded feature survives.
//  * Decoder: 17 sequential levels; level l has B=2^l nodes. X_P dead.
// R12 = R11 + per-level fused kernel (z+gates+LSTM+Y+NLL+feat) for levels
//       0..10 (B<=1024), grid = B/32 blocks, one launch per level.
//       All deps row-local in-block (R6-proven phases; no grid barriers,
//       no coop launch, z stays in LDS). Dispatches 53 -> 31.
//       Levels 11..16: R11's 3-kernel pipeline (unchanged).
// ---------------------------------------------------------------------------

#define LOG2PI 1.8378770664093453f

typedef __attribute__((ext_vector_type(8))) short short8;
typedef __attribute__((ext_vector_type(4))) float f32x4;

__device__ inline float frcp(float x) { return __builtin_amdgcn_rcpf(x); }
__device__ inline float fexp(float x) { return __expf(x); }
__device__ inline float flog(float x) { return __logf(x); }
__device__ inline float ftanh(float x) {
    float xc = fminf(fmaxf(x, -10.f), 10.f);
    float e = __expf(2.f * xc);
    return (e - 1.f) * frcp(e + 1.f);
}
__device__ inline float sigm(float x) {
    float xc = fminf(fmaxf(x, -30.f), 30.f);
    return frcp(1.f + __expf(-xc));
}

__device__ inline ushort f2b(float v) {
    union { float f; unsigned u; } x; x.f = v;
    unsigned r = x.u + 0x7fffu + ((x.u >> 16) & 1u);
    return (ushort)(r >> 16);
}
__device__ inline float b2f(ushort h) {
    union { unsigned u; float f; } x; x.u = ((unsigned)h) << 16; return x.f;
}

__device__ inline void gload16(const void* g, void* l) {
    __builtin_amdgcn_global_load_lds(
        (const __attribute__((address_space(1))) unsigned*)g,
        (__attribute__((address_space(3))) unsigned*)l, 16, 0, 0);
}

__device__ inline f32x4 mfma16(short8 a, short8 b, f32x4 c) {
    return __builtin_amdgcn_mfma_f32_16x16x32_bf16(a, b, c, 0, 0, 0);
}

__device__ inline float halfmax(float v) {
    #pragma unroll
    for (int o = 16; o >= 1; o >>= 1) v = fmaxf(v, __shfl_xor(v, o));
    return v;
}
__device__ inline float halfsum(float v) {
    #pragma unroll
    for (int o = 16; o >= 1; o >>= 1) v += __shfl_xor(v, o);
    return v;
}
__device__ inline float lse20(float t) {
    float m = halfmax(t);
    float s = halfsum(fexp(t - m));
    return m + flog(s);
}

// NLL for one node; yb = this half's 263-value bf16 Y row. Wave-collective.
__device__ inline float nll_node(const ushort* yb, const float* X,
                                 long long fi, int lane, bool& sw_out)
{
    const int half = lane >> 5, k = lane & 31;
    float v = (k < 20) ? b2f(yb[k]) : -INFINITY;
    float mm = halfmax(v);
    float se = halfsum((k < 20) ? fexp(v - mm) : 0.f);
    float lpi = v - mm - flog(se);
    float mx = 0, my = 0, rsx = 1, rsy = 1, rho = 0, hro = 0, cxy = 0;
    float ma = 0, mb2 = 0, rsa = 1, rsb = 1, rab = 0, hra = 0, cab = 0;
    float ms = 0, hrs = 0, csl = 0;
    if (k < 20) {
        mx = b2f(yb[20 + k]); my = b2f(yb[40 + k]);
        float lsx = b2f(yb[60 + k]), lsy = b2f(yb[80 + k]);
        rsx = fexp(-lsx); rsy = fexp(-lsy);
        rho = ftanh(b2f(yb[100 + k]));
        float omr = 1.f - rho * rho;
        hro = 0.5f * frcp(omr);
        cxy = LOG2PI + lsx + lsy + 0.5f * flog(omr);
        ma = b2f(yb[120 + k]); mb2 = b2f(yb[140 + k]);
        float lsa = b2f(yb[160 + k]), lsb = b2f(yb[180 + k]);
        rsa = fexp(-lsa); rsb = fexp(-lsb);
        rab = ftanh(b2f(yb[200 + k]));
        float omr2 = 1.f - rab * rab;
        hra = 0.5f * frcp(omr2);
        cab = LOG2PI + lsa + lsb + 0.5f * flog(omr2);
        ms = b2f(yb[220 + k]); float lss = b2f(yb[240 + k]);
        float rss = fexp(-lss);
        hrs = 0.5f * rss * rss;
        csl = 0.5f * LOG2PI + lss;
    }
    float lq0, lq1, lq2;
    {
        float q0 = b2f(yb[260]), q1 = b2f(yb[261]), q2 = b2f(yb[262]);
        float qm = fmaxf(q0, fmaxf(q1, q2));
        float l = flog(fexp(q0 - qm) + fexp(q1 - qm) + fexp(q2 - qm)) + qm;
        lq0 = q0 - l; lq1 = q1 - l; lq2 = q2 - l;
    }
    const float* pl = X + (size_t)(2 * fi + 1) * 8;
    const float* pr = X + (size_t)(2 * fi + 2) * 8;
    float res[2];
    #pragma unroll
    for (int s = 0; s < 2; ++s) {
        const float* pt = s ? pr : pl;
        float dx = pt[0], dy = pt[1], da = pt[2], db = pt[3], ds = pt[4];
        float t1 = -INFINITY, t2 = -INFINITY, t3 = -INFINITY;
        if (k < 20) {
            float zx = (dx - mx) * rsx, zy = (dy - my) * rsy;
            float Zz = zx * zx + zy * zy - 2.f * rho * zx * zy;
            t1 = lpi - Zz * hro - cxy;
            float za = (da - ma) * rsa, zb = (db - mb2) * rsb;
            float Z2 = za * za + zb * zb - 2.f * rab * za * zb;
            t2 = lpi - Z2 * hra - cab;
            float zs = ds - ms;
            t3 = lpi - zs * zs * hrs - csl;
        }
        float l1 = lse20(t1), l2 = lse20(t2), l3 = lse20(t3);
        float pen = -(pt[5] * lq0 + pt[6] * lq1 + pt[7] * lq2);
        res[s] = -(l1 + l2 + l3) + pen;
    }
    float Aval = half ? res[1] : res[0];
    float Bval = half ? res[0] : res[1];
    float direct = Aval + __shfl_xor(Aval, 32);
    float swapped = Bval + __shfl_xor(Bval, 32);
    sw_out = swapped < direct;
    return sw_out ? swapped : direct;
}

// Write child features into Ap rows 2fi+1, 2fi+2 (cols 8..263).
__device__ inline void feat_write_ap(ushort* Ap, const ushort* Hj,
                                     const ushort* Cj, long long fi, bool sw,
                                     int lane)
{
    const size_t rowL = 2 * (size_t)fi + 1;
    const int offL = sw ? 128 : 0;
    const int offR = 128 - offL;
    const int part = lane >> 5;
    const int c = (lane & 31) * 4;
    ushort4 vL = *(const ushort4*)((part ? Cj : Hj) + offL + c);
    ushort4 vR = *(const ushort4*)((part ? Cj : Hj) + offR + c);
    *(ushort4*)(Ap + rowL * 576 + 8 + part * 128 + c) = vL;
    *(ushort4*)(Ap + (rowL + 1) * 576 + 8 + part * 128 + c) = vR;
}

// ---------------------------------------------------------------------------
// level_fused: one launch per small level (B<=1024). Block = 32 nodes, grid
// = ceil(B/32). Phases (all deps row-local; R6-proven structure):
//  A: stage Asm[32][576 swz] = [X|F] from Ap (slots 0..32) + zero pad (65..71)
//  B: z = tanh(F @ Wz^T + b): zh -> Asm slots 33..64 (LDS), c_f -> Zc LDS
//  C: gates (K=576) + in-reg LSTM -> Hb/Cc global (level-local node rows)
//  D: 2x16 nodes: Y-MFMA (Hs from Hb same-block), bf16 Ysb, NLL, feat->Ap
// ---------------------------------------------------------------------------
__global__ __launch_bounds__(256) void level_fused(
    const float* __restrict__ X, ushort* __restrict__ Ap,
    const ushort* __restrict__ Wz, const float* __restrict__ fc_h_b,
    const ushort* __restrict__ Wg, const float* __restrict__ bg,
    const ushort* __restrict__ Wyp, const float* __restrict__ fc_b,
    ushort* __restrict__ Hb, ushort* __restrict__ Cc,
    float* __restrict__ loss, int B, long long nb, float scale)
{
    __shared__ char pool[53248] __attribute__((aligned(16)));
    __shared__ float lsum[4];
    ushort* Asm = (ushort*)pool;              // [32][576] slot-XOR swizzled
    ushort* Zc  = (ushort*)(pool + 36864);    // [32][256] c_f
    ushort* Hs  = (ushort*)pool;              // phase D overlay
    ushort* Ysb = (ushort*)pool;              // phase D overlay (after MFMA)

    const int tid = threadIdx.x;
    const int lane = tid & 63;
    const int wv  = tid >> 6;
    const int fr = lane & 15, fq = lane >> 4;
    const int gbase = blockIdx.x * 32;

    // ---- phase A ----
    for (int c = tid; c < 1280; c += 256) {
        const int r = c / 40, s5 = c - r * 40;
        const int s = s5 < 33 ? s5 : s5 + 32;     // 0..32 data, 65..71 pad
        const int ss = s ^ (r & 7);
        short8 v = {0, 0, 0, 0, 0, 0, 0, 0};
        if (s < 33) {
            int node = gbase + r; node = node < B ? node : B - 1;
            v = *(const short8*)(Ap + (size_t)(nb + node) * 576 + s * 8);
        }
        *(short8*)&Asm[r * 576 + ss * 8] = v;
    }
    __syncthreads();

    // ---- phase B: z (512 cols / 4 waves) ----
    {
        f32x4 acc[2][8] = {};
        for (int ks = 0; ks < 8; ++ks) {
            short8 a[2];
            #pragma unroll
            for (int mf = 0; mf < 2; ++mf) {
                const int r = mf * 16 + fr;
                const int ss = (1 + ks * 4 + fq) ^ (r & 7);
                a[mf] = *(const short8*)&Asm[r * 576 + ss * 8];
            }
            #pragma unroll
            for (int nf = 0; nf < 8; ++nf) {
                const short8 b = *(const short8*)(
                    Wz + (size_t)(wv * 128 + nf * 16 + fr) * 256 + ks * 32 + fq * 8);
                acc[0][nf] = mfma16(a[0], b, acc[0][nf]);
                acc[1][nf] = mfma16(a[1], b, acc[1][nf]);
            }
        }
        #pragma unroll
        for (int mf = 0; mf < 2; ++mf)
            #pragma unroll
            for (int nf = 0; nf < 8; ++nf)
                #pragma unroll
                for (int j = 0; j < 4; ++j) {
                    const int r = mf * 16 + fq * 4 + j;
                    const int col = wv * 128 + nf * 16 + fr;
                    const float z = ftanh(acc[mf][nf][j] + fc_h_b[col]);
                    if (col < 256) {
                        const int ss = (33 + (col >> 3)) ^ (r & 7);
                        Asm[r * 576 + ss * 8 + (col & 7)] = f2b(z);
                    } else {
                        Zc[r * 256 + (col - 256)] = f2b(z);
                    }
                }
    }
    __syncthreads();

    // ---- phase C: gates + LSTM (2 passes of 128 cols per wave) ----
    for (int p = 0; p < 2; ++p) {
        f32x4 acc[2][8] = {};
        const int cbase = wv * 256 + p * 128;
        for (int ks = 0; ks < 18; ++ks) {
            short8 a[2];
            #pragma unroll
            for (int mf = 0; mf < 2; ++mf) {
                const int r = mf * 16 + fr;
                const int ss = (ks * 4 + fq) ^ (r & 7);
                a[mf] = *(const short8*)&Asm[r * 576 + ss * 8];
            }
            #pragma unroll
            for (int nf = 0; nf < 8; ++nf) {
                const short8 b = *(const short8*)(
                    Wg + (size_t)(cbase + nf * 16 + fr) * 576 + ks * 32 + fq * 8);
                acc[0][nf] = mfma16(a[0], b, acc[0][nf]);
                acc[1][nf] = mfma16(a[1], b, acc[1][nf]);
            }
        }
        const int q = fr & 3;
        #pragma unroll
        for (int mf = 0; mf < 2; ++mf) {
            const int r = mf * 16 + fq * 4 + q;
            #pragma unroll
            for (int nf = 0; nf < 8; ++nf) {
                const int col = cbase + nf * 16 + fr;
                f32x4 v = acc[mf][nf];
                const float bb = bg[col];
                v[0] += bb; v[1] += bb; v[2] += bb; v[3] += bb;
                float gv[4];
                gv[q] = v[q];
                #pragma unroll
                for (int m = 1; m < 4; ++m)
                    gv[q ^ m] = __shfl_xor(v[q ^ m], m);
                const int jl = gbase + r;
                if (jl < B) {
                    const int t = col >> 2;
                    const float cf = b2f(Zc[r * 256 + t]);
                    const float c2 = sigm(gv[1]) * cf + sigm(gv[0]) * ftanh(gv[2]);
                    const float hv = sigm(gv[3]) * ftanh(c2);
                    Hb[(size_t)jl * 256 + t] = f2b(hv);
                    Cc[(size_t)jl * 256 + t] = f2b(c2);
                }
            }
        }
    }
    __syncthreads();

    // ---- phase D: 2 x 16 nodes: Y + NLL + feat write ----
    for (int sub = 0; sub < 2; ++sub) {
        const int n16 = gbase + sub * 16;
        if (n16 < B) {
            #pragma unroll
            for (int it = 0; it < 2; ++it) {
                const int i = it * 256 + tid;
                const int row = i >> 4, slot = i & 15;
                const int sl = slot ^ (row & 7);
                int gr = n16 * 2 + row;
                const int grmax = 2 * B - 1;
                gr = gr <= grmax ? gr : grmax;
                gload16(Hb + (size_t)gr * 128 + sl * 8, &Hs[(i - lane) * 8]);
            }
            __syncthreads();
            f32x4 acc[2][5] = {};
            #pragma unroll
            for (int ks = 0; ks < 4; ++ks) {
                short8 a[2];
                #pragma unroll
                for (int rf = 0; rf < 2; ++rf) {
                    const int row = rf * 16 + fr;
                    const int sl = (ks * 4 + fq) ^ (row & 7);
                    a[rf] = *(const short8*)&Hs[row * 128 + sl * 8];
                }
                #pragma unroll
                for (int n = 0; n < 5; ++n) {
                    const short8 b = *(const short8*)(
                        Wyp + (size_t)(wv * 80 + n * 16 + fr) * 128 + ks * 32 + fq * 8);
                    acc[0][n] = mfma16(a[0], b, acc[0][n]);
                    acc[1][n] = mfma16(a[1], b, acc[1][n]);
                }
            }
            __syncthreads();   // done reading Hs; Ysb overlays
            #pragma unroll
            for (int rf = 0; rf < 2; ++rf)
                #pragma unroll
                for (int n = 0; n < 5; ++n)
                    #pragma unroll
                    for (int j = 0; j < 4; ++j) {
                        const int row = rf * 16 + fq * 4 + j;
                        const int col = wv * 80 + n * 16 + fr;
                        if (col < 263)
                            Ysb[row * 272 + col] = f2b(acc[rf][n][j] + fc_b[col]);
                    }
            __syncthreads();
            float wsum = 0.f;
            #pragma unroll
            for (int s4 = 0; s4 < 4; ++s4) {
                const int jj = wv * 4 + s4;
                const int j = n16 + jj;
                if (j >= B) break;
                bool sw;
                const long long fi = nb + j;
                wsum += nll_node(&Ysb[(2 * jj + (lane >> 5)) * 272], X, fi, lane, sw);
                feat_write_ap(Ap, Hb + (size_t)j * 256, Cc + (size_t)j * 256,
                              fi, sw, lane);
            }
            if (lane == 0) lsum[wv] = wsum;
            __syncthreads();
            if (tid == 0)
                atomicAdd(loss, (lsum[0] + lsum[1] + lsum[2] + lsum[3]) * scale);
            __syncthreads();
        }
    }
}

// ---------------------------------------------------------------------------
// z_gemm: Z = tanh(F @ Wz^T + fc_h_b), F = Ap chunk cols 8..263 (K=256).
// z_h -> Ap cols 264..519; c_f -> Zcc. Grid (mg, 4). (large levels)
// ---------------------------------------------------------------------------
__global__ __launch_bounds__(256) void z_gemm(
    ushort* __restrict__ Apc,
    const ushort* __restrict__ Wz,
    const float* __restrict__ fc_h_b,
    ushort* __restrict__ Zcc,
    int M)
{
    __shared__ ushort As[128 * 64];
    __shared__ ushort Bs[128 * 64];
    const int tid = threadIdx.x;
    const int lane = tid & 63;
    const int w = tid >> 6;
    const int wr = w >> 1, wc = w & 1;
    const int fr = lane & 15, fq = lane >> 4;
    const int m0 = blockIdx.x * 128, n0 = blockIdx.y * 128;

    f32x4 acc[4][4] = {};

    #pragma unroll
    for (int k0 = 0; k0 < 256; k0 += 64) {
        __syncthreads();
        #pragma unroll
        for (int it = 0; it < 4; ++it) {
            const int i = it * 256 + tid;
            const int row = i >> 3, slot = i & 7;
            const int sl = slot ^ (row & 7);
            const int wbase = (i - lane) * 8;
            {
                int gm = m0 + row; gm = gm < M ? gm : M - 1;
                gload16(Apc + (size_t)gm * 576 + 8 + k0 + sl * 8, &As[wbase]);
            }
            {
                int gn = n0 + row; gn = gn < 512 ? gn : 511;
                gload16(Wz + (size_t)gn * 256 + k0 + sl * 8, &Bs[wbase]);
            }
        }
        __syncthreads();
        #pragma unroll
        for (int ks = 0; ks < 2; ++ks) {
            short8 af[4], bfr[4];
            #pragma unroll
            for (int mr = 0; mr < 4; ++mr) {
                const int row = wr * 64 + mr * 16 + fr;
                const int sl = (ks * 4 + fq) ^ (row & 7);
                af[mr] = *(const short8*)&As[row * 64 + sl * 8];
            }
            #pragma unroll
            for (int nc = 0; nc < 4; ++nc) {
                const int row = wc * 64 + nc * 16 + fr;
                const int sl = (ks * 4 + fq) ^ (row & 7);
                bfr[nc] = *(const short8*)&Bs[row * 64 + sl * 8];
            }
            #pragma unroll
            for (int mr = 0; mr < 4; ++mr)
                #pragma unroll
                for (int nc = 0; nc < 4; ++nc)
                    acc[mr][nc] = mfma16(af[mr], bfr[nc], acc[mr][nc]);
        }
    }

    #pragma unroll
    for (int mr = 0; mr < 4; ++mr) {
        #pragma unroll
        for (int j = 0; j < 4; ++j) {
            const int row = m0 + wr * 64 + mr * 16 + fq * 4 + j;
            if (row >= M) continue;
            #pragma unroll
            for (int nc = 0; nc < 4; ++nc) {
                const int col = n0 + wc * 64 + nc * 16 + fr;
                const float z = ftanh(acc[mr][nc][j] + fc_h_b[col]);
                if (col < 256)
                    Apc[(size_t)row * 576 + 264 + col] = f2b(z);
                else
                    Zcc[(size_t)row * 256 + (col - 256)] = f2b(z);
            }
        }
    }
}

// ---------------------------------------------------------------------------
// gates_lstm: G = Ap[j][0..575] @ Wg^T + bg (gate-interleaved), in-register
// LSTM epilogue -> H,C bf16. (large levels)
// ---------------------------------------------------------------------------
__global__ __launch_bounds__(256) void gates_lstm(
    const ushort* __restrict__ Apc,
    const ushort* __restrict__ Wg,
    const float*  __restrict__ bg,
    const ushort* __restrict__ Zcc,
    ushort* __restrict__ H, ushort* __restrict__ C, int M)
{
    __shared__ ushort As[128 * 64];
    __shared__ ushort Bs[128 * 64];
    const int tid = threadIdx.x;
    const int lane = tid & 63;
    const int w = tid >> 6;
    const int wr = w >> 1, wc = w & 1;
    const int fr = lane & 15, fq = lane >> 4;
    const int m0 = blockIdx.x * 128, n0 = blockIdx.y * 128;

    f32x4 acc[4][4] = {};

    #pragma unroll
    for (int k0 = 0; k0 < 576; k0 += 64) {
        __syncthreads();
        #pragma unroll
        for (int it = 0; it < 4; ++it) {
            const int i = it * 256 + tid;
            const int row = i >> 3, slot = i & 7;
            const int sl = slot ^ (row & 7);
            const int wbase = (i - lane) * 8;
            {
                int gm = m0 + row; gm = gm < M ? gm : M - 1;
                gload16(Apc + (size_t)gm * 576 + k0 + sl * 8, &As[wbase]);
            }
            gload16(Wg + (size_t)(n0 + row) * 576 + k0 + sl * 8, &Bs[wbase]);
        }
        __syncthreads();
        #pragma unroll
        for (int ks = 0; ks < 2; ++ks) {
            short8 af[4], bfr[4];
            #pragma unroll
            for (int mr = 0; mr < 4; ++mr) {
                const int row = wr * 64 + mr * 16 + fr;
                const int sl = (ks * 4 + fq) ^ (row & 7);
                af[mr] = *(const short8*)&As[row * 64 + sl * 8];
            }
            #pragma unroll
            for (int nc = 0; nc < 4; ++nc) {
                const int row = wc * 64 + nc * 16 + fr;
                const int sl = (ks * 4 + fq) ^ (row & 7);
                bfr[nc] = *(const short8*)&Bs[row * 64 + sl * 8];
            }
            #pragma unroll
            for (int mr = 0; mr < 4; ++mr)
                #pragma unroll
                for (int nc = 0; nc < 4; ++nc)
                    acc[mr][nc] = mfma16(af[mr], bfr[nc], acc[mr][nc]);
        }
    }

    const int q = fr & 3;
    #pragma unroll
    for (int mr = 0; mr < 4; ++mr) {
        const int node = m0 + wr * 64 + mr * 16 + fq * 4 + q;
        #pragma unroll
        for (int nc = 0; nc < 4; ++nc) {
            const int col = n0 + wc * 64 + nc * 16 + fr;
            f32x4 v = acc[mr][nc];
            const float b = bg[col];
            v[0] += b; v[1] += b; v[2] += b; v[3] += b;
            float gv[4];
            gv[q] = v[q];
            #pragma unroll
            for (int m = 1; m < 4; ++m)
                gv[q ^ m] = __shfl_xor(v[q ^ m], m);
            if (node < M) {
                const int t = (col >> 2) & 255;
                const float cf = b2f(Zcc[(size_t)node * 256 + t]);
                const float c2 = sigm(gv[1]) * cf + sigm(gv[0]) * ftanh(gv[2]);
                const float hv = sigm(gv[3]) * ftanh(c2);
                H[(size_t)node * 256 + t] = f2b(hv);
                C[(size_t)node * 256 + t] = f2b(c2);
            }
        }
    }
}

// ---------------------------------------------------------------------------
// ynll: Y-GEMM + NLL + swap + child-feature write. Block = 16 nodes.
// Phase-overlaid LDS pool (Hs 8KB / Ysb bf16 17.4KB). (large levels)
// ---------------------------------------------------------------------------
#define YS 272
__global__ __launch_bounds__(256) void ynll(
    const ushort* __restrict__ Hb, const ushort* __restrict__ Cc,
    const ushort* __restrict__ Wyp,
    const float* __restrict__ fc_b, const float* __restrict__ X,
    ushort* __restrict__ Ap, float* __restrict__ loss,
    int Bc, long long nb_fi, float scale, int writeFeat)
{
    __shared__ char pool[17408] __attribute__((aligned(16)));
    __shared__ float lsum[4];
    ushort* Hs  = (ushort*)pool;
    ushort* Ysb = (ushort*)pool;
    const int tid = threadIdx.x;
    const int lane = tid & 63;
    const int wv = tid >> 6;
    const int fr = lane & 15, fq = lane >> 4;
    const int n16 = blockIdx.x * 16;

    #pragma unroll
    for (int it = 0; it < 2; ++it) {
        const int i = it * 256 + tid;
        const int row = i >> 4, slot = i & 15;
        const int sl = slot ^ (row & 7);
        int gr = n16 * 2 + row;
        const int grmax = 2 * Bc - 1;
        gr = gr <= grmax ? gr : grmax;
        gload16(Hb + (size_t)gr * 128 + sl * 8, &Hs[(i - lane) * 8]);
    }
    __syncthreads();

    f32x4 acc[2][5] = {};
    #pragma unroll
    for (int ks = 0; ks < 4; ++ks) {
        short8 a[2];
        #pragma unroll
        for (int rf = 0; rf < 2; ++rf) {
            const int row = rf * 16 + fr;
            const int sl = (ks * 4 + fq) ^ (row & 7);
            a[rf] = *(const short8*)&Hs[row * 128 + sl * 8];
        }
        #pragma unroll
        for (int n = 0; n < 5; ++n) {
            const short8 b = *(const short8*)(
                Wyp + (size_t)(wv * 80 + n * 16 + fr) * 128 + ks * 32 + fq * 8);
            acc[0][n] = mfma16(a[0], b, acc[0][n]);
            acc[1][n] = mfma16(a[1], b, acc[1][n]);
        }
    }
    __syncthreads();

    #pragma unroll
    for (int rf = 0; rf < 2; ++rf)
        #pragma unroll
        for (int n = 0; n < 5; ++n)
            #pragma unroll
            for (int j = 0; j < 4; ++j) {
                const int row = rf * 16 + fq * 4 + j;
                const int col = wv * 80 + n * 16 + fr;
                if (col < 263)
                    Ysb[row * YS + col] = f2b(acc[rf][n][j] + fc_b[col]);
            }
    __syncthreads();

    float wsum = 0.f;
    #pragma unroll
    for (int s4 = 0; s4 < 4; ++s4) {
        const int jj = wv * 4 + s4;
        const int j = n16 + jj;
        if (j >= Bc) break;
        bool sw;
        const long long fi = nb_fi + j;
        wsum += nll_node(&Ysb[(2 * jj + (lane >> 5)) * YS], X, fi, lane, sw);
        if (writeFeat)
            feat_write_ap(Ap, Hb + (size_t)j * 256, Cc + (size_t)j * 256,
                          fi, sw, lane);
    }
    if (lane == 0) lsum[wv] = wsum;
    __syncthreads();
    if (tid == 0)
        atomicAdd(loss, (lsum[0] + lsum[1] + lsum[2] + lsum[3]) * scale);
}

// ---------------------------------------------------------------------------
// One-time repack + Ap prefill (vectorized), single launch.
// ---------------------------------------------------------------------------
__global__ __launch_bounds__(256) void pack_all(
    const float* __restrict__ fc_h_W, ushort* __restrict__ Wz,
    const float* __restrict__ Wih, const float* __restrict__ Whh,
    ushort* __restrict__ Wg,
    const float* __restrict__ bih, const float* __restrict__ bhh,
    float* __restrict__ bg,
    const float* __restrict__ fcW, ushort* __restrict__ Wy,
    const float* __restrict__ X, ushort* __restrict__ Ap, int nInt)
{
    int i = blockIdx.x * 256 + threadIdx.x;
    if (i < 131072) { Wz[i] = f2b(fc_h_W[i]); return; }
    i -= 131072;
    if (i < 589824) {
        int np = i / 576, c = i - np * 576;
        int n = (np & 3) * 256 + (np >> 2);
        float v = 0.f;
        if (c < 264) v = Wih[n * 264 + c];
        else if (c < 520) v = Whh[n * 256 + (c - 264)];
        Wg[i] = f2b(v);
        return;
    }
    i -= 589824;
    if (i < 1024) {
        int n = (i & 3) * 256 + (i >> 2);
        bg[i] = bih[n] + bhh[n];
        return;
    }
    i -= 1024;
    if (i < 40960) {
        int r = i / 128;
        Wy[i] = f2b(r < 263 ? fcW[i] : 0.f);
        return;
    }
    i -= 40960;
    if (i < nInt * 8) {
        int row = i >> 3, s = i & 7;
        if (s == 0) {
            const float* xs = X + (size_t)row * 8;
            short8 v;
            #pragma unroll
            for (int k = 0; k < 8; ++k)
                ((ushort*)&v)[k] = f2b(xs[k]);
            *(short8*)(Ap + (size_t)row * 576) = v;
        } else {
            short8 z = {0, 0, 0, 0, 0, 0, 0, 0};
            *(short8*)(Ap + (size_t)row * 576 + (64 + s) * 8) = z;  // cols 520..575
        }
    }
}

// ---------------------------------------------------------------------------
// Encoder: only the root feature matters. One block. Writes Ap[0][8..263].
// ---------------------------------------------------------------------------
__global__ __launch_bounds__(256) void encoder_root(
    const float* __restrict__ X, const float* __restrict__ Feature,
    const float* __restrict__ Wih, const float* __restrict__ Whh,
    const float* __restrict__ bih, const float* __restrict__ bhh,
    ushort* __restrict__ Ap)
{
    __shared__ float gsh[2][512];
    __shared__ float hc[2][256];
    const int t = threadIdx.x;
    for (int ch = 0; ch < 2; ++ch) {
        const int node = 1 + ch;
        const float* x = X + node * 8;
        const float* h = Feature + (size_t)node * 256;
        #pragma unroll
        for (int gi = 0; gi < 2; ++gi) {
            int g = t + gi * 256;
            float s = bih[g] + bhh[g];
            const float* wi = Wih + (size_t)g * 8;
            #pragma unroll
            for (int k = 0; k < 8; ++k) s += wi[k] * x[k];
            const float* wh = Whh + (size_t)g * 128;
            for (int k = 0; k < 128; ++k) s += wh[k] * h[k];
            gsh[ch][g] = s;
        }
    }
    __syncthreads();
    {
        int ch = t >> 7, u = t & 127;
        float i_ = gsh[ch][u], f_ = gsh[ch][128 + u];
        float gg = gsh[ch][256 + u], o_ = gsh[ch][384 + u];
        float c = Feature[(size_t)(1 + ch) * 256 + 128 + u];
        float c2 = sigm(f_) * c + sigm(i_) * ftanh(gg);
        hc[ch][u] = sigm(o_) * ftanh(c2);
        hc[ch][128 + u] = c2;
    }
    __syncthreads();
    Ap[8 + t] = f2b(hc[0][t] + hc[1][t]);
}

// ---------------------------------------------------------------------------
extern "C" void kernel_launch(void* const* d_in, const int* in_sizes, int n_in,
                              void* d_out, int out_size, void* d_ws, size_t ws_size,
                              hipStream_t stream)
{
    const float* X       = (const float*)d_in[0];
    const float* Feature = (const float*)d_in[1];
    const float* W_ih_e  = (const float*)d_in[3];
    const float* W_hh_e  = (const float*)d_in[4];
    const float* b_ih_e  = (const float*)d_in[5];
    const float* b_hh_e  = (const float*)d_in[6];
    const float* fc_h_W  = (const float*)d_in[7];
    const float* fc_h_b  = (const float*)d_in[8];
    const float* W_ih_d  = (const float*)d_in[9];
    const float* W_hh_d  = (const float*)d_in[10];
    const float* b_ih_d  = (const float*)d_in[11];
    const float* b_hh_d  = (const float*)d_in[12];
    const float* fc_W    = (const float*)d_in[13];
    const float* fc_b    = (const float*)d_in[14];
    const int Nnodes = in_sizes[0] / 8;       // 262143
    const int nInt = (Nnodes - 1) / 2;        // 131071 internal nodes

    float* out = (float*)d_out;
    hipMemsetAsync(d_out, 0, sizeof(float), stream);

    char* cur = (char*)d_ws;
    auto take = [&](size_t bytes) {
        char* p = cur;
        cur += (bytes + 255) & ~(size_t)255;
        return p;
    };
    ushort* Ap  = (ushort*)take((size_t)(nInt + 1) * 576 * 2);   // ~151 MB
    ushort* Wz  = (ushort*)take((size_t)512 * 256 * 2);
    ushort* Wg  = (ushort*)take((size_t)1024 * 576 * 2);
    ushort* Wy  = (ushort*)take((size_t)320 * 128 * 2);
    float*  bg  = (float*) take((size_t)1024 * 4);
    ushort* Zcc = (ushort*)take((size_t)65536 * 256 * 2);
    ushort* Hb  = (ushort*)take((size_t)65536 * 256 * 2);
    ushort* Cc  = (ushort*)take((size_t)65536 * 256 * 2);

    const int packTotal = 131072 + 589824 + 1024 + 40960 + nInt * 8;
    pack_all<<<(packTotal + 255) / 256, 256, 0, stream>>>(
        fc_h_W, Wz, W_ih_d, W_hh_d, Wg, b_ih_d, b_hh_d, bg, fc_W, Wy,
        X, Ap, nInt);

    encoder_root<<<1, 256, 0, stream>>>(X, Feature, W_ih_e, W_hh_e,
                                        b_ih_e, b_hh_e, Ap);

    // levels 0..10: one fused launch per level (B <= 1024)
    for (int l = 0; l <= 10; ++l) {
        const int B = 1 << l;
        const long long nb = B - 1;
        const float scale = 1.f / ((float)B * 17.f);
        level_fused<<<(B + 31) / 32, 256, 0, stream>>>(
            X, Ap, Wz, fc_h_b, Wg, bg, Wy, fc_b, Hb, Cc, out, B, nb, scale);
    }

    // levels 11..16: 3-kernel pipeline
    for (int l = 11; l < 17; ++l) {
        const int B = 1 << l;
        const long long nb = B - 1;
        const int writeFeat = (l < 16) ? 1 : 0;
        const float scale = 1.f / ((float)B * 17.f);
        const int mg = (B + 127) / 128;
        ushort* Apc = Ap + (size_t)nb * 576;
        z_gemm<<<dim3(mg, 4), 256, 0, stream>>>(Apc, Wz, fc_h_b, Zcc, B);
        gates_lstm<<<dim3(mg, 8), 256, 0, stream>>>(
            Apc, Wg, bg, Zcc, Hb, Cc, B);
        ynll<<<(B + 15) / 16, 256, 0, stream>>>(
            Hb, Cc, Wy, fc_b, X, Ap, out,
            B, nb, scale, writeFeat);
    }
}

// Round 13
// 1221.980 us; speedup vs baseline: 1.4535x; 1.4535x over previous
//
#include <hip/hip_runtime.h>
#include <hip/hip_bf16.h>
#include <math.h>

// ---------------------------------------------------------------------------
// D=256, LVL=17, MIX=20. N nodes = 2^18-1; internal = 2^17-1 = 131071.
//  * Encoder reads ORIGINAL Feature -> only root's encoded feature survives.
//  * Decoder: 17 sequential levels; level l has B=2^l nodes. X_P dead.
// R13 = R11 restored (best: 1231 us) + encoder merged into pack_all block 0.
//   Constraint learned from R6/R7/R12 failures: per-block weight streaming
//   is ~15-20 GB/s; any kernel whose blocks each read >~150 KB of weights
//   loses to the weight-sliced 3-kernel pipeline. Do not re-fuse levels.
// ---------------------------------------------------------------------------

#define LOG2PI 1.8378770664093453f

typedef __attribute__((ext_vector_type(8))) short short8;
typedef __attribute__((ext_vector_type(4))) float f32x4;

__device__ inline float frcp(float x) { return __builtin_amdgcn_rcpf(x); }
__device__ inline float fexp(float x) { return __expf(x); }
__device__ inline float flog(float x) { return __logf(x); }
__device__ inline float ftanh(float x) {
    float xc = fminf(fmaxf(x, -10.f), 10.f);
    float e = __expf(2.f * xc);
    return (e - 1.f) * frcp(e + 1.f);
}
__device__ inline float sigm(float x) {
    float xc = fminf(fmaxf(x, -30.f), 30.f);
    return frcp(1.f + __expf(-xc));
}

__device__ inline ushort f2b(float v) {
    union { float f; unsigned u; } x; x.f = v;
    unsigned r = x.u + 0x7fffu + ((x.u >> 16) & 1u);
    return (ushort)(r >> 16);
}
__device__ inline float b2f(ushort h) {
    union { unsigned u; float f; } x; x.u = ((unsigned)h) << 16; return x.f;
}

__device__ inline void gload16(const void* g, void* l) {
    __builtin_amdgcn_global_load_lds(
        (const __attribute__((address_space(1))) unsigned*)g,
        (__attribute__((address_space(3))) unsigned*)l, 16, 0, 0);
}

__device__ inline f32x4 mfma16(short8 a, short8 b, f32x4 c) {
    return __builtin_amdgcn_mfma_f32_16x16x32_bf16(a, b, c, 0, 0, 0);
}

__device__ inline float halfmax(float v) {
    #pragma unroll
    for (int o = 16; o >= 1; o >>= 1) v = fmaxf(v, __shfl_xor(v, o));
    return v;
}
__device__ inline float halfsum(float v) {
    #pragma unroll
    for (int o = 16; o >= 1; o >>= 1) v += __shfl_xor(v, o);
    return v;
}
__device__ inline float lse20(float t) {
    float m = halfmax(t);
    float s = halfsum(fexp(t - m));
    return m + flog(s);
}

// NLL for one node; yb = this half's 263-value bf16 Y row. Wave-collective.
__device__ inline float nll_node(const ushort* yb, const float* X,
                                 long long fi, int lane, bool& sw_out)
{
    const int half = lane >> 5, k = lane & 31;
    float v = (k < 20) ? b2f(yb[k]) : -INFINITY;
    float mm = halfmax(v);
    float se = halfsum((k < 20) ? fexp(v - mm) : 0.f);
    float lpi = v - mm - flog(se);
    float mx = 0, my = 0, rsx = 1, rsy = 1, rho = 0, hro = 0, cxy = 0;
    float ma = 0, mb2 = 0, rsa = 1, rsb = 1, rab = 0, hra = 0, cab = 0;
    float ms = 0, hrs = 0, csl = 0;
    if (k < 20) {
        mx = b2f(yb[20 + k]); my = b2f(yb[40 + k]);
        float lsx = b2f(yb[60 + k]), lsy = b2f(yb[80 + k]);
        rsx = fexp(-lsx); rsy = fexp(-lsy);
        rho = ftanh(b2f(yb[100 + k]));
        float omr = 1.f - rho * rho;
        hro = 0.5f * frcp(omr);
        cxy = LOG2PI + lsx + lsy + 0.5f * flog(omr);
        ma = b2f(yb[120 + k]); mb2 = b2f(yb[140 + k]);
        float lsa = b2f(yb[160 + k]), lsb = b2f(yb[180 + k]);
        rsa = fexp(-lsa); rsb = fexp(-lsb);
        rab = ftanh(b2f(yb[200 + k]));
        float omr2 = 1.f - rab * rab;
        hra = 0.5f * frcp(omr2);
        cab = LOG2PI + lsa + lsb + 0.5f * flog(omr2);
        ms = b2f(yb[220 + k]); float lss = b2f(yb[240 + k]);
        float rss = fexp(-lss);
        hrs = 0.5f * rss * rss;
        csl = 0.5f * LOG2PI + lss;
    }
    float lq0, lq1, lq2;
    {
        float q0 = b2f(yb[260]), q1 = b2f(yb[261]), q2 = b2f(yb[262]);
        float qm = fmaxf(q0, fmaxf(q1, q2));
        float l = flog(fexp(q0 - qm) + fexp(q1 - qm) + fexp(q2 - qm)) + qm;
        lq0 = q0 - l; lq1 = q1 - l; lq2 = q2 - l;
    }
    const float* pl = X + (size_t)(2 * fi + 1) * 8;
    const float* pr = X + (size_t)(2 * fi + 2) * 8;
    float res[2];
    #pragma unroll
    for (int s = 0; s < 2; ++s) {
        const float* pt = s ? pr : pl;
        float dx = pt[0], dy = pt[1], da = pt[2], db = pt[3], ds = pt[4];
        float t1 = -INFINITY, t2 = -INFINITY, t3 = -INFINITY;
        if (k < 20) {
            float zx = (dx - mx) * rsx, zy = (dy - my) * rsy;
            float Zz = zx * zx + zy * zy - 2.f * rho * zx * zy;
            t1 = lpi - Zz * hro - cxy;
            float za = (da - ma) * rsa, zb = (db - mb2) * rsb;
            float Z2 = za * za + zb * zb - 2.f * rab * za * zb;
            t2 = lpi - Z2 * hra - cab;
            float zs = ds - ms;
            t3 = lpi - zs * zs * hrs - csl;
        }
        float l1 = lse20(t1), l2 = lse20(t2), l3 = lse20(t3);
        float pen = -(pt[5] * lq0 + pt[6] * lq1 + pt[7] * lq2);
        res[s] = -(l1 + l2 + l3) + pen;
    }
    float Aval = half ? res[1] : res[0];
    float Bval = half ? res[0] : res[1];
    float direct = Aval + __shfl_xor(Aval, 32);
    float swapped = Bval + __shfl_xor(Bval, 32);
    sw_out = swapped < direct;
    return sw_out ? swapped : direct;
}

// Write child features into Ap rows 2fi+1, 2fi+2 (cols 8..263).
__device__ inline void feat_write_ap(ushort* Ap, const ushort* Hj,
                                     const ushort* Cj, long long fi, bool sw,
                                     int lane)
{
    const size_t rowL = 2 * (size_t)fi + 1;
    const int offL = sw ? 128 : 0;
    const int offR = 128 - offL;
    const int part = lane >> 5;
    const int c = (lane & 31) * 4;
    ushort4 vL = *(const ushort4*)((part ? Cj : Hj) + offL + c);
    ushort4 vR = *(const ushort4*)((part ? Cj : Hj) + offR + c);
    *(ushort4*)(Ap + rowL * 576 + 8 + part * 128 + c) = vL;
    *(ushort4*)(Ap + (rowL + 1) * 576 + 8 + part * 128 + c) = vR;
}

// ---------------------------------------------------------------------------
// z_gemm: Z = tanh(F @ Wz^T + fc_h_b), F = Ap chunk cols 8..263 (K=256).
// z_h -> Ap cols 264..519; c_f -> Zcc. Grid (mg, 4).
// ---------------------------------------------------------------------------
__global__ __launch_bounds__(256) void z_gemm(
    ushort* __restrict__ Apc,
    const ushort* __restrict__ Wz,
    const float* __restrict__ fc_h_b,
    ushort* __restrict__ Zcc,
    int M)
{
    __shared__ ushort As[128 * 64];
    __shared__ ushort Bs[128 * 64];
    const int tid = threadIdx.x;
    const int lane = tid & 63;
    const int w = tid >> 6;
    const int wr = w >> 1, wc = w & 1;
    const int fr = lane & 15, fq = lane >> 4;
    const int m0 = blockIdx.x * 128, n0 = blockIdx.y * 128;

    f32x4 acc[4][4] = {};

    #pragma unroll
    for (int k0 = 0; k0 < 256; k0 += 64) {
        __syncthreads();
        #pragma unroll
        for (int it = 0; it < 4; ++it) {
            const int i = it * 256 + tid;
            const int row = i >> 3, slot = i & 7;
            const int sl = slot ^ (row & 7);
            const int wbase = (i - lane) * 8;
            {
                int gm = m0 + row; gm = gm < M ? gm : M - 1;
                gload16(Apc + (size_t)gm * 576 + 8 + k0 + sl * 8, &As[wbase]);
            }
            {
                int gn = n0 + row; gn = gn < 512 ? gn : 511;
                gload16(Wz + (size_t)gn * 256 + k0 + sl * 8, &Bs[wbase]);
            }
        }
        __syncthreads();
        #pragma unroll
        for (int ks = 0; ks < 2; ++ks) {
            short8 af[4], bfr[4];
            #pragma unroll
            for (int mr = 0; mr < 4; ++mr) {
                const int row = wr * 64 + mr * 16 + fr;
                const int sl = (ks * 4 + fq) ^ (row & 7);
                af[mr] = *(const short8*)&As[row * 64 + sl * 8];
            }
            #pragma unroll
            for (int nc = 0; nc < 4; ++nc) {
                const int row = wc * 64 + nc * 16 + fr;
                const int sl = (ks * 4 + fq) ^ (row & 7);
                bfr[nc] = *(const short8*)&Bs[row * 64 + sl * 8];
            }
            #pragma unroll
            for (int mr = 0; mr < 4; ++mr)
                #pragma unroll
                for (int nc = 0; nc < 4; ++nc)
                    acc[mr][nc] = mfma16(af[mr], bfr[nc], acc[mr][nc]);
        }
    }

    #pragma unroll
    for (int mr = 0; mr < 4; ++mr) {
        #pragma unroll
        for (int j = 0; j < 4; ++j) {
            const int row = m0 + wr * 64 + mr * 16 + fq * 4 + j;
            if (row >= M) continue;
            #pragma unroll
            for (int nc = 0; nc < 4; ++nc) {
                const int col = n0 + wc * 64 + nc * 16 + fr;
                const float z = ftanh(acc[mr][nc][j] + fc_h_b[col]);
                if (col < 256)
                    Apc[(size_t)row * 576 + 264 + col] = f2b(z);
                else
                    Zcc[(size_t)row * 256 + (col - 256)] = f2b(z);
            }
        }
    }
}

// ---------------------------------------------------------------------------
// gates_lstm: G = Ap[j][0..575] @ Wg^T + bg (gate-interleaved), in-register
// LSTM epilogue -> H,C bf16. Branch-free single-source staging.
// ---------------------------------------------------------------------------
__global__ __launch_bounds__(256) void gates_lstm(
    const ushort* __restrict__ Apc,
    const ushort* __restrict__ Wg,
    const float*  __restrict__ bg,
    const ushort* __restrict__ Zcc,
    ushort* __restrict__ H, ushort* __restrict__ C, int M)
{
    __shared__ ushort As[128 * 64];
    __shared__ ushort Bs[128 * 64];
    const int tid = threadIdx.x;
    const int lane = tid & 63;
    const int w = tid >> 6;
    const int wr = w >> 1, wc = w & 1;
    const int fr = lane & 15, fq = lane >> 4;
    const int m0 = blockIdx.x * 128, n0 = blockIdx.y * 128;

    f32x4 acc[4][4] = {};

    #pragma unroll
    for (int k0 = 0; k0 < 576; k0 += 64) {
        __syncthreads();
        #pragma unroll
        for (int it = 0; it < 4; ++it) {
            const int i = it * 256 + tid;
            const int row = i >> 3, slot = i & 7;
            const int sl = slot ^ (row & 7);
            const int wbase = (i - lane) * 8;
            {
                int gm = m0 + row; gm = gm < M ? gm : M - 1;
                gload16(Apc + (size_t)gm * 576 + k0 + sl * 8, &As[wbase]);
            }
            gload16(Wg + (size_t)(n0 + row) * 576 + k0 + sl * 8, &Bs[wbase]);
        }
        __syncthreads();
        #pragma unroll
        for (int ks = 0; ks < 2; ++ks) {
            short8 af[4], bfr[4];
            #pragma unroll
            for (int mr = 0; mr < 4; ++mr) {
                const int row = wr * 64 + mr * 16 + fr;
                const int sl = (ks * 4 + fq) ^ (row & 7);
                af[mr] = *(const short8*)&As[row * 64 + sl * 8];
            }
            #pragma unroll
            for (int nc = 0; nc < 4; ++nc) {
                const int row = wc * 64 + nc * 16 + fr;
                const int sl = (ks * 4 + fq) ^ (row & 7);
                bfr[nc] = *(const short8*)&Bs[row * 64 + sl * 8];
            }
            #pragma unroll
            for (int mr = 0; mr < 4; ++mr)
                #pragma unroll
                for (int nc = 0; nc < 4; ++nc)
                    acc[mr][nc] = mfma16(af[mr], bfr[nc], acc[mr][nc]);
        }
    }

    const int q = fr & 3;
    #pragma unroll
    for (int mr = 0; mr < 4; ++mr) {
        const int node = m0 + wr * 64 + mr * 16 + fq * 4 + q;
        #pragma unroll
        for (int nc = 0; nc < 4; ++nc) {
            const int col = n0 + wc * 64 + nc * 16 + fr;
            f32x4 v = acc[mr][nc];
            const float b = bg[col];
            v[0] += b; v[1] += b; v[2] += b; v[3] += b;
            float gv[4];
            gv[q] = v[q];
            #pragma unroll
            for (int m = 1; m < 4; ++m)
                gv[q ^ m] = __shfl_xor(v[q ^ m], m);
            if (node < M) {
                const int t = (col >> 2) & 255;
                const float cf = b2f(Zcc[(size_t)node * 256 + t]);
                const float c2 = sigm(gv[1]) * cf + sigm(gv[0]) * ftanh(gv[2]);
                const float hv = sigm(gv[3]) * ftanh(c2);
                H[(size_t)node * 256 + t] = f2b(hv);
                C[(size_t)node * 256 + t] = f2b(c2);
            }
        }
    }
}

// ---------------------------------------------------------------------------
// ynll: Y-GEMM + NLL + swap + child-feature write. Block = 16 nodes.
// Phase-overlaid LDS pool: phase 1 Hs[32][128] swz (8 KB) -> Y MFMA;
// phase 2 Ysb[32][272] bf16 (17.4 KB) -> NLL + feat write.
// ---------------------------------------------------------------------------
#define YS 272
__global__ __launch_bounds__(256) void ynll(
    const ushort* __restrict__ Hb, const ushort* __restrict__ Cc,
    const ushort* __restrict__ Wyp,
    const float* __restrict__ fc_b, const float* __restrict__ X,
    ushort* __restrict__ Ap, float* __restrict__ loss,
    int Bc, long long nb_fi, float scale, int writeFeat)
{
    __shared__ char pool[17408] __attribute__((aligned(16)));
    __shared__ float lsum[4];
    ushort* Hs  = (ushort*)pool;   // phase 1
    ushort* Ysb = (ushort*)pool;   // phase 2 overlay
    const int tid = threadIdx.x;
    const int lane = tid & 63;
    const int wv = tid >> 6;
    const int fr = lane & 15, fq = lane >> 4;
    const int n16 = blockIdx.x * 16;

    #pragma unroll
    for (int it = 0; it < 2; ++it) {
        const int i = it * 256 + tid;
        const int row = i >> 4, slot = i & 15;
        const int sl = slot ^ (row & 7);
        int gr = n16 * 2 + row;
        const int grmax = 2 * Bc - 1;
        gr = gr <= grmax ? gr : grmax;
        gload16(Hb + (size_t)gr * 128 + sl * 8, &Hs[(i - lane) * 8]);
    }
    __syncthreads();

    f32x4 acc[2][5] = {};
    #pragma unroll
    for (int ks = 0; ks < 4; ++ks) {
        short8 a[2];
        #pragma unroll
        for (int rf = 0; rf < 2; ++rf) {
            const int row = rf * 16 + fr;
            const int sl = (ks * 4 + fq) ^ (row & 7);
            a[rf] = *(const short8*)&Hs[row * 128 + sl * 8];
        }
        #pragma unroll
        for (int n = 0; n < 5; ++n) {
            const short8 b = *(const short8*)(
                Wyp + (size_t)(wv * 80 + n * 16 + fr) * 128 + ks * 32 + fq * 8);
            acc[0][n] = mfma16(a[0], b, acc[0][n]);
            acc[1][n] = mfma16(a[1], b, acc[1][n]);
        }
    }
    __syncthreads();   // all waves done reading Hs (Ysb overlays it)

    #pragma unroll
    for (int rf = 0; rf < 2; ++rf)
        #pragma unroll
        for (int n = 0; n < 5; ++n)
            #pragma unroll
            for (int j = 0; j < 4; ++j) {
                const int row = rf * 16 + fq * 4 + j;
                const int col = wv * 80 + n * 16 + fr;
                if (col < 263)
                    Ysb[row * YS + col] = f2b(acc[rf][n][j] + fc_b[col]);
            }
    __syncthreads();

    float wsum = 0.f;
    #pragma unroll
    for (int s4 = 0; s4 < 4; ++s4) {
        const int jj = wv * 4 + s4;
        const int j = n16 + jj;
        if (j >= Bc) break;
        bool sw;
        const long long fi = nb_fi + j;
        wsum += nll_node(&Ysb[(2 * jj + (lane >> 5)) * YS], X, fi, lane, sw);
        if (writeFeat)
            feat_write_ap(Ap, Hb + (size_t)j * 256, Cc + (size_t)j * 256,
                          fi, sw, lane);
    }
    if (lane == 0) lsum[wv] = wsum;
    __syncthreads();
    if (tid == 0)
        atomicAdd(loss, (lsum[0] + lsum[1] + lsum[2] + lsum[3]) * scale);
}

// ---------------------------------------------------------------------------
// One-time repack + Ap prefill + encoder (block 0), single launch.
// Encoder and pack touch disjoint data (encoder writes Ap[0][8..263];
// pack writes weights, Ap X-cols and zero pad) -> safe to merge.
// ---------------------------------------------------------------------------
__global__ __launch_bounds__(256) void pack_all(
    const float* __restrict__ fc_h_W, ushort* __restrict__ Wz,
    const float* __restrict__ Wih, const float* __restrict__ Whh,
    ushort* __restrict__ Wg,
    const float* __restrict__ bih, const float* __restrict__ bhh,
    float* __restrict__ bg,
    const float* __restrict__ fcW, ushort* __restrict__ Wy,
    const float* __restrict__ X, ushort* __restrict__ Ap, int nInt,
    const float* __restrict__ Feature,
    const float* __restrict__ Wih_e, const float* __restrict__ Whh_e,
    const float* __restrict__ bih_e, const float* __restrict__ bhh_e)
{
    __shared__ float gsh[2][512];
    __shared__ float hc[2][256];
    if (blockIdx.x == 0) {
        // ---- encoder: only the root feature matters ----
        const int t = threadIdx.x;
        for (int ch = 0; ch < 2; ++ch) {
            const int node = 1 + ch;
            const float* x = X + node * 8;
            const float* h = Feature + (size_t)node * 256;
            #pragma unroll
            for (int gi = 0; gi < 2; ++gi) {
                int g = t + gi * 256;
                float s = bih_e[g] + bhh_e[g];
                const float* wi = Wih_e + (size_t)g * 8;
                #pragma unroll
                for (int k = 0; k < 8; ++k) s += wi[k] * x[k];
                const float* wh = Whh_e + (size_t)g * 128;
                for (int k = 0; k < 128; ++k) s += wh[k] * h[k];
                gsh[ch][g] = s;
            }
        }
        __syncthreads();
        {
            int ch = t >> 7, u = t & 127;
            float i_ = gsh[ch][u], f_ = gsh[ch][128 + u];
            float gg = gsh[ch][256 + u], o_ = gsh[ch][384 + u];
            float c = Feature[(size_t)(1 + ch) * 256 + 128 + u];
            float c2 = sigm(f_) * c + sigm(i_) * ftanh(gg);
            hc[ch][u] = sigm(o_) * ftanh(c2);
            hc[ch][128 + u] = c2;
        }
        __syncthreads();
        Ap[8 + t] = f2b(hc[0][t] + hc[1][t]);
        return;
    }
    int i = (blockIdx.x - 1) * 256 + threadIdx.x;
    if (i < 131072) { Wz[i] = f2b(fc_h_W[i]); return; }
    i -= 131072;
    if (i < 589824) {
        int np = i / 576, c = i - np * 576;
        int n = (np & 3) * 256 + (np >> 2);
        float v = 0.f;
        if (c < 264) v = Wih[n * 264 + c];
        else if (c < 520) v = Whh[n * 256 + (c - 264)];
        Wg[i] = f2b(v);
        return;
    }
    i -= 589824;
    if (i < 1024) {
        int n = (i & 3) * 256 + (i >> 2);
        bg[i] = bih[n] + bhh[n];
        return;
    }
    i -= 1024;
    if (i < 40960) {
        int r = i / 128;
        Wy[i] = f2b(r < 263 ? fcW[i] : 0.f);
        return;
    }
    i -= 40960;
    if (i < nInt * 8) {
        int row = i >> 3, s = i & 7;
        if (s == 0) {
            const float* xs = X + (size_t)row * 8;
            short8 v;
            #pragma unroll
            for (int k = 0; k < 8; ++k)
                ((ushort*)&v)[k] = f2b(xs[k]);
            *(short8*)(Ap + (size_t)row * 576) = v;
        } else {
            short8 z = {0, 0, 0, 0, 0, 0, 0, 0};
            *(short8*)(Ap + (size_t)row * 576 + (64 + s) * 8) = z;  // cols 520..575
        }
    }
}

// ---------------------------------------------------------------------------
extern "C" void kernel_launch(void* const* d_in, const int* in_sizes, int n_in,
                              void* d_out, int out_size, void* d_ws, size_t ws_size,
                              hipStream_t stream)
{
    const float* X       = (const float*)d_in[0];
    const float* Feature = (const float*)d_in[1];
    const float* W_ih_e  = (const float*)d_in[3];
    const float* W_hh_e  = (const float*)d_in[4];
    const float* b_ih_e  = (const float*)d_in[5];
    const float* b_hh_e  = (const float*)d_in[6];
    const float* fc_h_W  = (const float*)d_in[7];
    const float* fc_h_b  = (const float*)d_in[8];
    const float* W_ih_d  = (const float*)d_in[9];
    const float* W_hh_d  = (const float*)d_in[10];
    const float* b_ih_d  = (const float*)d_in[11];
    const float* b_hh_d  = (const float*)d_in[12];
    const float* fc_W    = (const float*)d_in[13];
    const float* fc_b    = (const float*)d_in[14];
    const int Nnodes = in_sizes[0] / 8;       // 262143
    const int nInt = (Nnodes - 1) / 2;        // 131071 internal nodes

    float* out = (float*)d_out;
    hipMemsetAsync(d_out, 0, sizeof(float), stream);

    char* cur = (char*)d_ws;
    auto take = [&](size_t bytes) {
        char* p = cur;
        cur += (bytes + 255) & ~(size_t)255;
        return p;
    };
    ushort* Ap  = (ushort*)take((size_t)(nInt + 1) * 576 * 2);   // ~151 MB
    ushort* Wz  = (ushort*)take((size_t)512 * 256 * 2);
    ushort* Wg  = (ushort*)take((size_t)1024 * 576 * 2);
    ushort* Wy  = (ushort*)take((size_t)320 * 128 * 2);
    float*  bg  = (float*) take((size_t)1024 * 4);
    ushort* Zcc = (ushort*)take((size_t)65536 * 256 * 2);
    ushort* Hb  = (ushort*)take((size_t)65536 * 256 * 2);
    ushort* Cc  = (ushort*)take((size_t)65536 * 256 * 2);

    const int packTotal = 131072 + 589824 + 1024 + 40960 + nInt * 8;
    pack_all<<<1 + (packTotal + 255) / 256, 256, 0, stream>>>(
        fc_h_W, Wz, W_ih_d, W_hh_d, Wg, b_ih_d, b_hh_d, bg, fc_W, Wy,
        X, Ap, nInt,
        Feature, W_ih_e, W_hh_e, b_ih_e, b_hh_e);

    for (int l = 0; l < 17; ++l) {
        const int B = 1 << l;
        const long long nb = B - 1;
        const int writeFeat = (l < 16) ? 1 : 0;
        const float scale = 1.f / ((float)B * 17.f);
        const int mg = (B + 127) / 128;
        ushort* Apc = Ap + (size_t)nb * 576;
        z_gemm<<<dim3(mg, 4), 256, 0, stream>>>(Apc, Wz, fc_h_b, Zcc, B);
        gates_lstm<<<dim3(mg, 8), 256, 0, stream>>>(
            Apc, Wg, bg, Zcc, Hb, Cc, B);
        ynll<<<(B + 15) / 16, 256, 0, stream>>>(
            Hb, Cc, Wy, fc_b, X, Ap, out,
            B, nb, scale, writeFeat);
    }
}